// Round 1
// baseline (62.542 us; speedup 1.0000x reference)
//
#include <hip/hip_runtime.h>
#include <math.h>

// Quantum autoencoder forward, analytically reduced:
//   - wires 10..13 are |0> until the swap test, so simulate only the 10-qubit
//     register (1024 complex amplitudes) per batch sample, in LDS.
//   - swap test vs |000> reduces to P(aux=1) = 0.5*(1 - sum_{t=000}|psi_{x,t}|^2)
//     where the trash bits t are the 3 LSBs of the 10-qubit index
//     (wire 0 = MSB ... wire 9 = LSB, matching the reference's reshape order).
//   - the per-layer CNOT ring is a basis permutation -> one gather, not 10 gates.

#define NQ     10
#define DIM    1024          // 2^10
#define NDEPTH 4
#define NGATE  (NQ + NDEPTH * NQ)   // 50 RX gates total

// inverse of the CNOT-ring permutation:
// forward (applied to state): for w=0..9 sequentially, bit_{(w+1)%10} ^= bit_w
// (wire w lives at bit position 9-w). inverse = same xors, reverse order.
__device__ inline int cnot_ring_inv(int i) {
#pragma unroll
    for (int w = NQ - 1; w >= 0; --w) {
        int cb   = (i >> (NQ - 1 - w)) & 1;
        int tpos = NQ - 1 - ((w + 1) % NQ);
        i ^= cb << tpos;
    }
    return i;
}

__global__ __launch_bounds__(512) void qae_kernel(
    const float* __restrict__ features,   // [B, 10]
    const float* __restrict__ weights,    // [4, 10] flat
    float* __restrict__ out)              // [B]
{
    __shared__ float sre[DIM];
    __shared__ float sim_[DIM];
    __shared__ float gc[NGATE];
    __shared__ float gs[NGATE];
    __shared__ float part[2];

    const int b   = blockIdx.x;
    const int tid = threadIdx.x;          // 0..511

    // ---- init state |0...0> and precompute all gate cos/sin ----
    sre[tid]        = 0.0f;  sim_[tid]        = 0.0f;
    sre[tid + 512]  = 0.0f;  sim_[tid + 512]  = 0.0f;
    if (tid == 0) sre[0] = 1.0f;
    if (tid < NGATE) {
        float ang = (tid < NQ) ? features[b * NQ + tid] : weights[tid - NQ];
        float h = 0.5f * ang;
        gc[tid] = cosf(h);
        gs[tid] = sinf(h);
    }
    __syncthreads();

    // ---- helper lambda: RX(theta) on wire w, pair owned exclusively by tid ----
    auto rx = [&](int w, float c, float s) {
        int bitpos = NQ - 1 - w;
        int mask   = 1 << bitpos;
        int i0 = ((tid >> bitpos) << (bitpos + 1)) | (tid & (mask - 1));
        int i1 = i0 | mask;
        float a0r = sre[i0], a0i = sim_[i0];
        float a1r = sre[i1], a1i = sim_[i1];
        // RX = [[c, -i s], [-i s, c]]
        sre[i0]  = fmaf(c, a0r,  s * a1i);
        sim_[i0] = fmaf(c, a0i, -s * a1r);
        sre[i1]  = fmaf(c, a1r,  s * a0i);
        sim_[i1] = fmaf(c, a1i, -s * a0r);
    };

    // ---- AngleEmbedding: RX(features[b,w]) on wire w ----
    for (int w = 0; w < NQ; ++w) {
        rx(w, gc[w], gs[w]);
        __syncthreads();
    }

    // ---- BasicEntanglerLayers ----
    for (int l = 0; l < NDEPTH; ++l) {
        for (int w = 0; w < NQ; ++w) {
            int g = NQ + l * NQ + w;
            rx(w, gc[g], gs[g]);
            __syncthreads();
        }
        // CNOT ring as one permutation gather: new[j] = old[perm_inv(j)]
        int j0 = tid, j1 = tid + 512;
        int s0 = cnot_ring_inv(j0);
        int s1 = cnot_ring_inv(j1);
        float r0 = sre[s0], m0 = sim_[s0];
        float r1 = sre[s1], m1 = sim_[s1];
        __syncthreads();
        sre[j0] = r0; sim_[j0] = m0;
        sre[j1] = r1; sim_[j1] = m1;
        __syncthreads();
    }

    // ---- swap test (analytic): p = 0.5*(1 - sum_{i: i&7==0} |psi_i|^2) ----
    float acc = 0.0f;
    if (tid < 128) {
        int i = tid << 3;                 // trash bits (3 LSBs) == 0
        acc = sre[i] * sre[i] + sim_[i] * sim_[i];
#pragma unroll
        for (int off = 32; off > 0; off >>= 1)
            acc += __shfl_down(acc, off, 64);
    }
    if (tid == 0)  part[0] = acc;
    if (tid == 64) part[1] = acc;
    __syncthreads();
    if (tid == 0)
        out[b] = 0.5f * (1.0f - (part[0] + part[1]));
}

extern "C" void kernel_launch(void* const* d_in, const int* in_sizes, int n_in,
                              void* d_out, int out_size, void* d_ws, size_t ws_size,
                              hipStream_t stream) {
    const float* features = (const float*)d_in[0];   // [B,10] float32
    const float* weights  = (const float*)d_in[1];   // [4,10] float32
    float*       out      = (float*)d_out;           // [B] float32

    int B = in_sizes[0] / NQ;                        // 256
    qae_kernel<<<B, 512, 0, stream>>>(features, weights, out);
}